// Round 3
// baseline (17.732 us; speedup 1.0000x reference)
//
#include <hip/hip_runtime.h>
#include <hip/hip_bf16.h>
#include <cstdint>

#define N 2048
#define BS 16
#define F_OUT 40
#define MAXDEG 256
#define LOG2E 1.44269504088896340736f

// ws layout:
//   byte 0      : float xT[N*BS]  (x transposed: xT[j*16+b] = x[b*N+j]) 128 KB
//   byte 131072 : float scal[32]  ([0]=s1*log2e, [1]=s2*log2e, [2+b]=mean_b)

// ---- prep: transpose x, per-batch means, s1/s2 (16 blocks, parallel) ------
__global__ __launch_bounds__(256) void k_prep(const float* __restrict__ x,
                                              const float* __restrict__ W,
                                              const float* __restrict__ a,
                                              float* __restrict__ xT,
                                              float* __restrict__ scal) {
    const int b = blockIdx.x;          // one block per batch
    const int t = threadIdx.x;
    const float4* xb4 = reinterpret_cast<const float4*>(x + (size_t)b * N);
    float s = 0.f;
    #pragma unroll
    for (int it = 0; it < N / (256 * 4); ++it) {
        const int k4 = t + it * 256;
        const float4 v = xb4[k4];
        const int k = k4 * 4;
        xT[(k + 0) * BS + b] = v.x;
        xT[(k + 1) * BS + b] = v.y;
        xT[(k + 2) * BS + b] = v.z;
        xT[(k + 3) * BS + b] = v.w;
        s += v.x + v.y + v.z + v.w;
    }
    __shared__ float sd[256];
    sd[t] = s; __syncthreads();
    for (int off = 128; off; off >>= 1) {
        if (t < off) sd[t] += sd[t + off];
        __syncthreads();
    }
    if (t == 0) scal[2 + b] = sd[0] * (1.0f / N);

    if (b == 0 && t < 64) {            // wave 0 of block 0: s1, s2
        float p1 = 0.f, p2 = 0.f;
        if (t < F_OUT) {
            const float w = W[t];
            p1 = w * a[t];
            p2 = w * a[F_OUT + t];
        }
        #pragma unroll
        for (int off = 32; off; off >>= 1) {
            p1 += __shfl_xor(p1, off);
            p2 += __shfl_xor(p2, off);
        }
        if (t == 0) { scal[0] = p1 * LOG2E; scal[1] = p2 * LOG2E; }
    }
}

// ---- main: one block per row i ---------------------------------------------
// lanes remapped to (neighbor-slot ng = lane>>4, batch b16 = lane&15):
// one xT gather instruction touches only 4 distinct 64B lines.
__global__ __launch_bounds__(256) void k_main(const float* __restrict__ adj,
                                              const float* __restrict__ xT,
                                              const float* __restrict__ scal,
                                              const float* __restrict__ W,
                                              float* __restrict__ out) {
    const int i = blockIdx.x;
    const int t = threadIdx.x;
    const int wv = t >> 6, lane = t & 63;
    const int b16 = lane & 15;
    const int ng  = lane >> 4;

    __shared__ unsigned short list[MAXDEG];
    __shared__ int wcnt[4];
    __shared__ int s_cnt;
    __shared__ float sdd[4][16], sdw[4][16];
    __shared__ float p16[16];

    // adj row (8 KB) coalesced
    const float4* arow = reinterpret_cast<const float4*>(adj + (size_t)i * N);
    float4 v0 = arow[wv * 128 + lane];
    float4 v1 = arow[wv * 128 + 64 + lane];

    // ballot-compact neighbor indices into LDS
    unsigned long long m[2][4];
    m[0][0] = __ballot(v0.x > 0.f);
    m[0][1] = __ballot(v0.y > 0.f);
    m[0][2] = __ballot(v0.z > 0.f);
    m[0][3] = __ballot(v0.w > 0.f);
    m[1][0] = __ballot(v1.x > 0.f);
    m[1][1] = __ballot(v1.y > 0.f);
    m[1][2] = __ballot(v1.z > 0.f);
    m[1][3] = __ballot(v1.w > 0.f);
    int cnt = 0;
    #pragma unroll
    for (int it = 0; it < 2; ++it)
        cnt += __popcll(m[it][0]) + __popcll(m[it][1]) +
               __popcll(m[it][2]) + __popcll(m[it][3]);
    if (lane == 0) wcnt[wv] = cnt;
    __syncthreads();

    int base = 0;
    for (int u = 0; u < wv; ++u) base += wcnt[u];
    const unsigned long long lt = (1ull << lane) - 1ull;
    #pragma unroll
    for (int it = 0; it < 2; ++it) {
        const int f4idx = wv * 128 + it * 64 + lane;
        #pragma unroll
        for (int k = 0; k < 4; ++k) {
            const unsigned long long mask = m[it][k];
            if ((mask >> lane) & 1ull) {
                const int pos = base + __popcll(mask & lt);
                if (pos < MAXDEG)
                    list[pos] = (unsigned short)(f4idx * 4 + k);
            }
            base += __popcll(mask);
        }
    }
    if (t == 0) {
        const int tot = wcnt[0] + wcnt[1] + wcnt[2] + wcnt[3];
        s_cnt = tot < MAXDEG ? tot : MAXDEG;
    }
    __syncthreads();

    const int deg = s_cnt;
    const float s1 = scal[0], s2 = scal[1];
    const float xiv = xT[i * BS + b16];      // one 64B line, broadcast
    const float zi2 = s1 * xiv;

    float d = 0.f, w = 0.f;
    for (int idx = wv * 4 + ng; idx < deg; idx += 16) {
        const int jn = list[idx];            // LDS broadcast per 16-lane group
        const float xj = xT[jn * BS + b16];  // 4 distinct 64B lines per wave
        const float z2 = fmaf(s2, xj, zi2);  // z*log2(e), sign preserved
        const float e = (z2 > 0.f) ? exp2f(z2) : 0.f;
        d += e;
        w = fmaf(e, xj, w);
    }
    // combine the 4 neighbor-slots within the wave
    d += __shfl_xor(d, 16); d += __shfl_xor(d, 32);
    w += __shfl_xor(w, 16); w += __shfl_xor(w, 32);
    if (lane < 16) { sdd[wv][lane] = d; sdw[wv][lane] = w; }
    __syncthreads();

    if (t < BS) {
        const float dt = sdd[0][t] + sdd[1][t] + sdd[2][t] + sdd[3][t];
        const float wt = sdw[0][t] + sdw[1][t] + sdw[2][t] + sdw[3][t];
        // all-invalid row: reference softmax is uniform over N -> mean(x[b,:])
        p16[t] = (dt > 0.f) ? (wt / dt) : scal[2 + t];
    }
    __syncthreads();

    for (int idx = t; idx < BS * F_OUT; idx += 256) {
        const int b = idx / F_OUT;
        const int f = idx - b * F_OUT;
        const float v = p16[b] * W[f];
        out[((size_t)(b * N + i)) * F_OUT + f] = (v > 0.f) ? v : expm1f(v);
    }
}

extern "C" void kernel_launch(void* const* d_in, const int* in_sizes, int n_in,
                              void* d_out, int out_size, void* d_ws, size_t ws_size,
                              hipStream_t stream) {
    const float* x   = (const float*)d_in[0];
    const float* adj = (const float*)d_in[1];
    // d_in[2] (ext_input) and d_in[3] (side_input) are unused by the reference
    const float* W   = (const float*)d_in[4];
    const float* a   = (const float*)d_in[5];
    float* out = (float*)d_out;

    char* ws = (char*)d_ws;
    float* xT   = (float*)ws;
    float* scal = (float*)(ws + (size_t)N * BS * sizeof(float));

    k_prep<<<BS, 256, 0, stream>>>(x, W, a, xT, scal);
    k_main<<<N, 256, 0, stream>>>(adj, xT, scal, W, out);
}

// Round 4
// 17.005 us; speedup vs baseline: 1.0427x; 1.0427x over previous
//
#include <hip/hip_runtime.h>
#include <hip/hip_bf16.h>
#include <cstdint>

#define N 2048
#define BS 16
#define F_OUT 40
#define MAXDEG 256
#define LOG2E 1.44269504088896340736f

#if defined(__has_builtin)
#if __has_builtin(__builtin_amdgcn_exp2f)
#define EXP2(x) __builtin_amdgcn_exp2f(x)
#endif
#endif
#ifndef EXP2
#define EXP2(x) exp2f(x)
#endif

// One block per adjacency row i. 256 threads = 4 waves.
// - adj row (8 KB) loaded coalesced, ballot-compacted neighbor list -> LDS
// - s1 = W.a1, s2 = W.a2 recomputed per-wave (40 MACs, hides under adj latency)
// - wave wv owns batches {wv, wv+4, wv+8, wv+12}, processed INTERLEAVED:
//   one pass over the list issues 4 independent gathers + 4 exp/fma chains,
//   all shuffle-reductions deferred to the end (one latency exposure, not 4)
// - valid logit z = s1*xi + s2*xj (iff adj>0 and z>0); exp never overflows
//   (z bounded ~13), so single-pass softmax without max subtraction
// - all-invalid row -> reference softmax uniform over N -> mean(x[b,:])
// - elu epilogue via native exp2 (no expm1f libcall)
__global__ __launch_bounds__(256) void k_fused(const float* __restrict__ x,
                                               const float* __restrict__ adj,
                                               const float* __restrict__ W,
                                               const float* __restrict__ a,
                                               float* __restrict__ out) {
    const int i = blockIdx.x;
    const int t = threadIdx.x;
    const int wv = t >> 6, lane = t & 63;

    __shared__ unsigned short list[MAXDEG];
    __shared__ int wcnt[4];
    __shared__ int s_cnt;

    // ---- adj row loads first (longest latency) ----
    const float4* arow = reinterpret_cast<const float4*>(adj + (size_t)i * N);
    const float4 v0 = arow[wv * 128 + lane];
    const float4 v1 = arow[wv * 128 + 64 + lane];

    // ---- s1, s2 per-wave (no LDS, no barrier; overlaps adj latency) ----
    const float wl = (lane < F_OUT) ? W[lane] : 0.f;
    float p1 = (lane < F_OUT) ? wl * a[lane] : 0.f;
    float p2 = (lane < F_OUT) ? wl * a[F_OUT + lane] : 0.f;
    #pragma unroll
    for (int off = 32; off; off >>= 1) {
        p1 += __shfl_xor(p1, off);
        p2 += __shfl_xor(p2, off);
    }
    const float s1 = p1 * LOG2E, s2 = p2 * LOG2E;

    // ---- ballot-compact adj row into LDS list ----
    unsigned long long m[2][4];
    m[0][0] = __ballot(v0.x > 0.f);
    m[0][1] = __ballot(v0.y > 0.f);
    m[0][2] = __ballot(v0.z > 0.f);
    m[0][3] = __ballot(v0.w > 0.f);
    m[1][0] = __ballot(v1.x > 0.f);
    m[1][1] = __ballot(v1.y > 0.f);
    m[1][2] = __ballot(v1.z > 0.f);
    m[1][3] = __ballot(v1.w > 0.f);
    int cnt = 0;
    #pragma unroll
    for (int it = 0; it < 2; ++it)
        cnt += __popcll(m[it][0]) + __popcll(m[it][1]) +
               __popcll(m[it][2]) + __popcll(m[it][3]);
    if (lane == 0) wcnt[wv] = cnt;
    __syncthreads();

    int base = 0;
    for (int u = 0; u < wv; ++u) base += wcnt[u];
    const unsigned long long lt = (1ull << lane) - 1ull;
    #pragma unroll
    for (int it = 0; it < 2; ++it) {
        const int f4idx = wv * 128 + it * 64 + lane;
        #pragma unroll
        for (int k = 0; k < 4; ++k) {
            const unsigned long long mask = m[it][k];
            if ((mask >> lane) & 1ull) {
                const int pos = base + __popcll(mask & lt);
                if (pos < MAXDEG)
                    list[pos] = (unsigned short)(f4idx * 4 + k);
            }
            base += __popcll(mask);
        }
    }
    if (t == 0) {
        const int tot = wcnt[0] + wcnt[1] + wcnt[2] + wcnt[3];
        s_cnt = tot < MAXDEG ? tot : MAXDEG;
    }
    __syncthreads();

    const int deg = s_cnt;
    const float* __restrict__ xb0 = x + (size_t)(wv)      * N;
    const float* __restrict__ xb1 = x + (size_t)(wv + 4)  * N;
    const float* __restrict__ xb2 = x + (size_t)(wv + 8)  * N;
    const float* __restrict__ xb3 = x + (size_t)(wv + 12) * N;
    const float zi0 = s1 * xb0[i];
    const float zi1 = s1 * xb1[i];
    const float zi2 = s1 * xb2[i];
    const float zi3 = s1 * xb3[i];

    float d0 = 0.f, w0 = 0.f, d1 = 0.f, w1 = 0.f;
    float d2 = 0.f, w2 = 0.f, d3 = 0.f, w3 = 0.f;
    for (int tt = lane; tt < deg; tt += 64) {
        const int jn = list[tt];
        // 4 independent gathers in flight
        const float xj0 = xb0[jn];
        const float xj1 = xb1[jn];
        const float xj2 = xb2[jn];
        const float xj3 = xb3[jn];
        float z, e;
        z = fmaf(s2, xj0, zi0); e = (z > 0.f) ? EXP2(z) : 0.f; d0 += e; w0 = fmaf(e, xj0, w0);
        z = fmaf(s2, xj1, zi1); e = (z > 0.f) ? EXP2(z) : 0.f; d1 += e; w1 = fmaf(e, xj1, w1);
        z = fmaf(s2, xj2, zi2); e = (z > 0.f) ? EXP2(z) : 0.f; d2 += e; w2 = fmaf(e, xj2, w2);
        z = fmaf(s2, xj3, zi3); e = (z > 0.f) ? EXP2(z) : 0.f; d3 += e; w3 = fmaf(e, xj3, w3);
    }
    // one deferred reduction phase for all 4 batches
    #pragma unroll
    for (int off = 32; off; off >>= 1) {
        d0 += __shfl_xor(d0, off); w0 += __shfl_xor(w0, off);
        d1 += __shfl_xor(d1, off); w1 += __shfl_xor(w1, off);
        d2 += __shfl_xor(d2, off); w2 += __shfl_xor(w2, off);
        d3 += __shfl_xor(d3, off); w3 += __shfl_xor(w3, off);
    }

    float pd[4] = {d0, d1, d2, d3};
    float pw[4] = {w0, w1, w2, w3};
    #pragma unroll
    for (int b4 = 0; b4 < 4; ++b4) {
        const int b = wv + b4 * 4;
        float p;
        if (pd[b4] > 0.f) {                 // wave-uniform (post-reduction)
            p = pw[b4] / pd[b4];
        } else {
            // all logits invalid -> softmax uniform over N -> mean(x[b,:])
            const float4* xv = reinterpret_cast<const float4*>(x + (size_t)b * N);
            float s = 0.f;
            for (int k = lane; k < N / 4; k += 64) {
                const float4 vv = xv[k];
                s += vv.x + vv.y + vv.z + vv.w;
            }
            #pragma unroll
            for (int off = 32; off; off >>= 1) s += __shfl_xor(s, off);
            p = s * (1.0f / N);
        }
        if (lane < F_OUT) {
            const float v = p * wl;
            const float o = (v > 0.f) ? v : (EXP2(v * LOG2E) - 1.0f);
            out[((size_t)(b * N + i)) * F_OUT + lane] = o;
        }
    }
}

extern "C" void kernel_launch(void* const* d_in, const int* in_sizes, int n_in,
                              void* d_out, int out_size, void* d_ws, size_t ws_size,
                              hipStream_t stream) {
    const float* x   = (const float*)d_in[0];
    const float* adj = (const float*)d_in[1];
    // d_in[2] (ext_input) and d_in[3] (side_input) are unused by the reference
    const float* W   = (const float*)d_in[4];
    const float* a   = (const float*)d_in[5];
    float* out = (float*)d_out;

    k_fused<<<N, 256, 0, stream>>>(x, adj, W, a, out);
}

// Round 5
// 15.685 us; speedup vs baseline: 1.1305x; 1.0842x over previous
//
#include <hip/hip_runtime.h>
#include <hip/hip_bf16.h>
#include <cstdint>

#define N 2048
#define BS 16
#define F_OUT 40
#define MAXDEG 256
#define LOG2E 1.44269504088896340736f

#if defined(__has_builtin)
#if __has_builtin(__builtin_amdgcn_exp2f)
#define EXP2(x) __builtin_amdgcn_exp2f(x)
#endif
#endif
#ifndef EXP2
#define EXP2(x) exp2f(x)
#endif

// One block per adjacency row i. 256 threads = 4 waves. (Round-2 structure —
// best measured at 16.1 us — with native-exp2 ELU epilogue.)
//  - adj row (8 KB) coalesced float4, ballot-compacted neighbor list -> LDS
//  - wave 0 computes s1 = W.a1, s2 = W.a2 (40 MACs), broadcast via LDS
//  - wave wv handles batches {wv, wv+4, wv+8, wv+12} sequentially: scalar
//    softmax over neighbors, p = sum(e*xj)/sum(e)
//  - valid logit z = s1*xi + s2*xj (iff adj>0 and z>0); z bounded (~13), so
//    single-pass softmax without max subtraction
//  - all-invalid row -> reference softmax uniform over N -> mean(x[b,:])
__global__ __launch_bounds__(256) void k_fused(const float* __restrict__ x,
                                               const float* __restrict__ adj,
                                               const float* __restrict__ W,
                                               const float* __restrict__ a,
                                               float* __restrict__ out) {
    const int i = blockIdx.x;
    const int t = threadIdx.x;
    const int wv = t >> 6, lane = t & 63;

    __shared__ unsigned short list[MAXDEG];
    __shared__ int wcnt[4];
    __shared__ int s_cnt;
    __shared__ float s_s1, s_s2;

    // ---- issue adj-row loads early (latency overlap with s1/s2 compute) ----
    const float4* arow = reinterpret_cast<const float4*>(adj + (size_t)i * N);
    float4 v0 = arow[wv * 128 + lane];
    float4 v1 = arow[wv * 128 + 64 + lane];

    // ---- s1, s2 (wave 0 only; independent loads overlap adj latency) ----
    if (wv == 0) {
        float p1 = 0.f, p2 = 0.f;
        if (lane < F_OUT) {
            const float w = W[lane];
            p1 = w * a[lane];
            p2 = w * a[F_OUT + lane];
        }
        #pragma unroll
        for (int off = 32; off; off >>= 1) {
            p1 += __shfl_xor(p1, off);
            p2 += __shfl_xor(p2, off);
        }
        if (lane == 0) { s_s1 = p1 * LOG2E; s_s2 = p2 * LOG2E; }
    }

    // ---- ballot compaction of adj row into LDS list ----
    unsigned long long m[2][4];
    int cnt = 0;
    m[0][0] = __ballot(v0.x > 0.f);
    m[0][1] = __ballot(v0.y > 0.f);
    m[0][2] = __ballot(v0.z > 0.f);
    m[0][3] = __ballot(v0.w > 0.f);
    m[1][0] = __ballot(v1.x > 0.f);
    m[1][1] = __ballot(v1.y > 0.f);
    m[1][2] = __ballot(v1.z > 0.f);
    m[1][3] = __ballot(v1.w > 0.f);
    #pragma unroll
    for (int it = 0; it < 2; ++it)
        cnt += __popcll(m[it][0]) + __popcll(m[it][1]) +
               __popcll(m[it][2]) + __popcll(m[it][3]);
    if (lane == 0) wcnt[wv] = cnt;
    __syncthreads();

    int base = 0;
    for (int u = 0; u < wv; ++u) base += wcnt[u];
    const unsigned long long lt = (1ull << lane) - 1ull;
    #pragma unroll
    for (int it = 0; it < 2; ++it) {
        const int f4idx = wv * 128 + it * 64 + lane;
        #pragma unroll
        for (int k = 0; k < 4; ++k) {
            const unsigned long long mask = m[it][k];
            if ((mask >> lane) & 1ull) {
                const int pos = base + __popcll(mask & lt);
                if (pos < MAXDEG)
                    list[pos] = (unsigned short)(f4idx * 4 + k);
            }
            base += __popcll(mask);
        }
    }
    if (t == 0) {
        int tot = wcnt[0] + wcnt[1] + wcnt[2] + wcnt[3];
        s_cnt = tot < MAXDEG ? tot : MAXDEG;
    }
    __syncthreads();

    const int deg = s_cnt;
    const float s1 = s_s1, s2 = s_s2;
    const float wl = (lane < F_OUT) ? W[lane] : 0.f;

    #pragma unroll
    for (int bb = 0; bb < 4; ++bb) {
        const int b = wv + bb * 4;
        const float* __restrict__ xb = x + b * N;
        const float zi2 = s1 * xb[i];

        float d = 0.f, ws = 0.f;
        for (int tt = lane; tt < deg; tt += 64) {
            const int jn = list[tt];
            const float xj = xb[jn];
            const float z2 = fmaf(s2, xj, zi2);  // z*log2(e); sign preserved
            const float e = (z2 > 0.f) ? EXP2(z2) : 0.f;
            d += e;
            ws = fmaf(e, xj, ws);
        }
        #pragma unroll
        for (int off = 32; off; off >>= 1) {
            d += __shfl_xor(d, off);
            ws += __shfl_xor(ws, off);
        }

        float p;
        if (d > 0.f) {            // wave-uniform (post-reduction)
            p = ws / d;
        } else {
            // all logits invalid -> reference softmax is uniform over N
            float s = 0.f;
            for (int k = lane; k < N; k += 64) s += xb[k];
            #pragma unroll
            for (int off = 32; off; off >>= 1) s += __shfl_xor(s, off);
            p = s * (1.0f / N);
        }

        if (lane < F_OUT) {
            const float v = p * wl;
            out[((size_t)(b * N + i)) * F_OUT + lane] =
                (v > 0.f) ? v : (EXP2(v * LOG2E) - 1.0f);
        }
    }
}

extern "C" void kernel_launch(void* const* d_in, const int* in_sizes, int n_in,
                              void* d_out, int out_size, void* d_ws, size_t ws_size,
                              hipStream_t stream) {
    const float* x   = (const float*)d_in[0];
    const float* adj = (const float*)d_in[1];
    // d_in[2] (ext_input) and d_in[3] (side_input) are unused by the reference
    const float* W   = (const float*)d_in[4];
    const float* a   = (const float*)d_in[5];
    float* out = (float*)d_out;

    k_fused<<<N, 256, 0, stream>>>(x, adj, W, a, out);
}